// Round 3
// baseline (827.825 us; speedup 1.0000x reference)
//
#include <hip/hip_runtime.h>

// LSTM RNN_20263655702953 — MI355X (gfx950), round 7.
//
// Reference quirk: hs[:, -1, :] selects BATCH index 511 => single sequential
// LSTM chain (1024 steps, H=64), then (1024,64)@(64,2) projection.
//
// R7: SINGLE-WAVE recurrence — eliminate the per-step barrier + LDS gate
// exchange entirely. R4/R5/R6 all assigned gate g -> wave g, forcing unit
// l's four gates through LDS+barrier every step (~half the step per
// VALUBusy=48% at 996cy/step). R5/R6 proved the h-path must avoid LDS
// latency (readlane wins); R7 removes the OTHER LDS round-trip by giving
// lane l ALL FOUR gate rows {l, 64+l, 128+l, 192+l}:
//   - i,f,g,o for unit l are lane-local => c,h update needs NO exchange.
//   - h broadcast stays on zero-latency readlane; each of the 64 RL now
//     feeds 4 FMAs (w[4][64] = 256 VGPRs of weights per lane).
//   - Zero barriers / zero LDS ops in the 1024-step loop. hist written
//     directly (1 coalesced 256B store/step, vmcnt never drained in-loop).
// Waves 1-3: stage x, then sleep at the pre-projection barrier, then help
// with the (1024,64)@(64,2) projection.
// Cost model: ~364 instr/step ≈ 720cy issue + ~80cy act tail ≈ 800cy/step
// vs R4's measured ~996cy.

#define T_LEN 1024
#define BATCH 512
#define HID   64

__device__ __forceinline__ float fast_rcp(float x) {
    return __builtin_amdgcn_rcpf(x);  // v_rcp_f32, ~1e-7 rel err
}
__device__ __forceinline__ float fast_tanh(float x) {
    // 1 - 2/(e^{2x}+1); saturates correctly for |x| large
    return 1.0f - 2.0f * fast_rcp(__expf(2.0f * x) + 1.0f);
}

__global__ __launch_bounds__(256, 1)
void lstm_seq_kernel(const float* __restrict__ x,
                     const float* __restrict__ W_ih,
                     const float* __restrict__ W_hh,
                     const float* __restrict__ b_ih,
                     const float* __restrict__ b_hh,
                     const float* __restrict__ W_fc,
                     const float* __restrict__ b_fc,
                     float* __restrict__ out,
                     float* __restrict__ hist)   // d_ws: 1024*64 floats
{
    __shared__ float xs[2 * T_LEN];         // 8 KB: x[:,511,:]

    const int tid  = threadIdx.x;
    const int lane = tid & 63;
    const int wave = tid >> 6;

    // ---- stage x[:,511,:] into LDS (all 4 waves, one-time)
    for (int j = 0; j < 4; ++j) {
        int t = tid + j * 256;              // 0..1023
        const float2 v = *(const float2*)(x + (size_t)(t * BATCH + (BATCH - 1)) * 2);
        xs[2 * t]     = v.x;
        xs[2 * t + 1] = v.y;
    }
    __syncthreads();                        // xs visible to wave 0

    if (wave == 0) {
        // ---- preload all 4 gate rows for unit `lane` into VGPRs
        // row(g) = g*64 + lane ; w[g][0..63] = W_hh[row(g), :]
        float w[4][HID];
        float wi0[4], wi1[4], bs[4];
        #pragma unroll
        for (int g = 0; g < 4; ++g) {
            const int row = g * HID + lane;
            const float4* wr = (const float4*)(W_hh + row * HID);
            #pragma unroll
            for (int k = 0; k < HID / 4; ++k) {
                float4 v = wr[k];
                w[g][4*k+0] = v.x; w[g][4*k+1] = v.y;
                w[g][4*k+2] = v.z; w[g][4*k+3] = v.w;
            }
            wi0[g] = W_ih[row * 2 + 0];
            wi1[g] = W_ih[row * 2 + 1];
            bs[g]  = b_ih[row] + b_hh[row];
        }

        float hval = 0.0f;   // lane l holds h[l]
        float cval = 0.0f;   // lane l holds c[l]

        for (int t = 0; t < T_LEN; ++t) {
            const float2 xv = *(const float2*)(xs + 2 * t);   // uniform bcast
            const int hb = __float_as_int(hval);

            // seed accumulators with bias + x-part (8 independent FMAs:
            // also spaces the hval->readlane hazard)
            float ai = fmaf(wi1[0], xv.y, fmaf(wi0[0], xv.x, bs[0]));
            float af = fmaf(wi1[1], xv.y, fmaf(wi0[1], xv.x, bs[1]));
            float ag = fmaf(wi1[2], xv.y, fmaf(wi0[2], xv.x, bs[2]));
            float ao = fmaf(wi1[3], xv.y, fmaf(wi0[3], xv.x, bs[3]));

            int hsA[16], hsB[16];

            // ---- RL batch 0 (h[0..15])
            #pragma unroll
            for (int k = 0; k < 16; ++k) hsA[k] = __builtin_amdgcn_readlane(hb, k);
            __builtin_amdgcn_sched_barrier(0);
            // ---- FMA batch 0 (4 gates x 16) + RL batch 1
            #pragma unroll
            for (int k = 0; k < 16; ++k) {
                const float hk = __int_as_float(hsA[k]);
                ai = fmaf(w[0][k], hk, ai);
                af = fmaf(w[1][k], hk, af);
                ag = fmaf(w[2][k], hk, ag);
                ao = fmaf(w[3][k], hk, ao);
            }
            #pragma unroll
            for (int k = 0; k < 16; ++k) hsB[k] = __builtin_amdgcn_readlane(hb, 16 + k);
            __builtin_amdgcn_sched_barrier(0);
            // ---- FMA batch 1 + RL batch 2 (reuse hsA)
            #pragma unroll
            for (int k = 0; k < 16; ++k) {
                const float hk = __int_as_float(hsB[k]);
                ai = fmaf(w[0][16+k], hk, ai);
                af = fmaf(w[1][16+k], hk, af);
                ag = fmaf(w[2][16+k], hk, ag);
                ao = fmaf(w[3][16+k], hk, ao);
            }
            #pragma unroll
            for (int k = 0; k < 16; ++k) hsA[k] = __builtin_amdgcn_readlane(hb, 32 + k);
            __builtin_amdgcn_sched_barrier(0);
            // ---- FMA batch 2 + RL batch 3 (reuse hsB)
            #pragma unroll
            for (int k = 0; k < 16; ++k) {
                const float hk = __int_as_float(hsA[k]);
                ai = fmaf(w[0][32+k], hk, ai);
                af = fmaf(w[1][32+k], hk, af);
                ag = fmaf(w[2][32+k], hk, ag);
                ao = fmaf(w[3][32+k], hk, ao);
            }
            #pragma unroll
            for (int k = 0; k < 16; ++k) hsB[k] = __builtin_amdgcn_readlane(hb, 48 + k);
            __builtin_amdgcn_sched_barrier(0);
            // ---- FMA batch 3
            #pragma unroll
            for (int k = 0; k < 16; ++k) {
                const float hk = __int_as_float(hsB[k]);
                ai = fmaf(w[0][48+k], hk, ai);
                af = fmaf(w[1][48+k], hk, af);
                ag = fmaf(w[2][48+k], hk, ag);
                ao = fmaf(w[3][48+k], hk, ao);
            }

            // ---- activations (3 sigmoid + 1 tanh, independent chains)
            const float gi = fast_rcp(1.0f + __expf(-ai));
            const float gf = fast_rcp(1.0f + __expf(-af));
            const float go = fast_rcp(1.0f + __expf(-ao));
            const float gg = fmaf(2.0f, fast_rcp(1.0f + __expf(-2.0f * ag)), -1.0f);

            // ---- lane-local update (NO exchange!)
            cval = fmaf(gf, cval, gi * gg);
            hval = go * fast_tanh(cval);

            // h history: direct coalesced 256B store; never waited on in-loop
            hist[t * HID + lane] = hval;
        }
    }

    __syncthreads();  // wave0's hist stores drained (vmcnt 0) & visible

    // ---- projection: out[t,o] = b_fc[o] + dot(W_fc[o,:], hist[t,:])
    #pragma unroll
    for (int j = 0; j < 8; ++j) {
        const int idx = tid + j * 256;      // 0..2047, coalesced stores
        const int t   = idx >> 1;
        const int o   = idx & 1;
        const float4* hv4 = (const float4*)(hist + t * HID);
        const float4* wv  = (const float4*)(W_fc + o * HID);
        float p0 = 0.f, p1 = 0.f, p2 = 0.f, p3 = 0.f;
        #pragma unroll
        for (int k = 0; k < HID / 4; ++k) {
            float4 h4 = hv4[k], w4 = wv[k];
            p0 = fmaf(h4.x, w4.x, p0);
            p1 = fmaf(h4.y, w4.y, p1);
            p2 = fmaf(h4.z, w4.z, p2);
            p3 = fmaf(h4.w, w4.w, p3);
        }
        out[idx] = b_fc[o] + ((p0 + p1) + (p2 + p3));
    }
}

extern "C" void kernel_launch(void* const* d_in, const int* in_sizes, int n_in,
                              void* d_out, int out_size, void* d_ws, size_t ws_size,
                              hipStream_t stream) {
    const float* x    = (const float*)d_in[0];
    const float* W_ih = (const float*)d_in[1];
    const float* W_hh = (const float*)d_in[2];
    const float* b_ih = (const float*)d_in[3];
    const float* b_hh = (const float*)d_in[4];
    const float* W_fc = (const float*)d_in[5];
    const float* b_fc = (const float*)d_in[6];
    float* out  = (float*)d_out;
    float* hist = (float*)d_ws;   // needs 1024*64*4 = 256 KB

    lstm_seq_kernel<<<dim3(1), dim3(256), 0, stream>>>(
        x, W_ih, W_hh, b_ih, b_hh, W_fc, b_fc, out, hist);
}